// Round 5
// baseline (479.079 us; speedup 1.0000x reference)
//
#include <hip/hip_runtime.h>
#include <hip/hip_bf16.h>

#define NEG_SLOPE 0.2f
#define EPSF 1e-16f

typedef __attribute__((ext_vector_type(8))) short bf16x8;
typedef __attribute__((ext_vector_type(4))) float f32x4;

__device__ inline unsigned short f2bf(float x) {
  unsigned int u = __float_as_uint(x);
  return (unsigned short)((u + 0x7fffu + ((u >> 16) & 1u)) >> 16);
}
__device__ inline float bf2f(unsigned short h) {
  return __uint_as_float(((unsigned int)h) << 16);
}

// -------------------- W prep: Wt_{hi,lo}[c][k] bf16 (linear transpose) --------------------
__global__ __launch_bounds__(256) void prep_w_kernel(const float* __restrict__ W,
                                                     unsigned short* __restrict__ wt_hi,
                                                     unsigned short* __restrict__ wt_lo) {
  int idx = blockIdx.x * 256 + threadIdx.x;  // (k:512, c:64)
  if (idx >= 512 * 64) return;
  int k = idx >> 6, c = idx & 63;
  float w = W[idx];
  unsigned short h = f2bf(w);
  unsigned short l = f2bf(w - bf2f(h));
  wt_hi[c * 512 + k] = h;
  wt_lo[c * 512 + k] = l;
}

// -------------------- GEMM1 via bf16 MFMA, LDS-free, split precision --------------------
// wave w owns rows [w*16, w*16+16) x all 64 cols. A frags straight from x (coalesced,
// read-once); B frags from L2-resident pre-transposed Wt hi/lo.
__global__ __launch_bounds__(256, 4) void gemm1_kernel(const float* __restrict__ x,
                                                       const unsigned short* __restrict__ wt_hi,
                                                       const unsigned short* __restrict__ wt_lo,
                                                       float* __restrict__ h1, int N) {
  const int lane = threadIdx.x & 63;
  const int wtile = (blockIdx.x * 256 + threadIdx.x) >> 6;  // global wave id
  const int r0 = wtile * 16;
  if (r0 >= N) return;
  const int rowA = r0 + (lane & 15);
  const bool avalid = rowA < N;
  const int kofs = (lane >> 4) * 8;
  const float* ap = x + (size_t)rowA * 512 + kofs;
  const int cbase = lane & 15;

  f32x4 acc[4] = {};

#pragma unroll 2
  for (int k0 = 0; k0 < 512; k0 += 32) {
    float4 a0 = make_float4(0.f, 0.f, 0.f, 0.f), a1 = make_float4(0.f, 0.f, 0.f, 0.f);
    if (avalid) {
      a0 = *(const float4*)(ap + k0);
      a1 = *(const float4*)(ap + k0 + 4);
    }
    float av[8] = {a0.x, a0.y, a0.z, a0.w, a1.x, a1.y, a1.z, a1.w};
    bf16x8 ah, al;
#pragma unroll
    for (int j = 0; j < 8; ++j) {
      unsigned short hb = f2bf(av[j]);
      ah[j] = (short)hb;
      al[j] = (short)f2bf(av[j] - bf2f(hb));
    }
#pragma unroll
    for (int ct = 0; ct < 4; ++ct) {
      const size_t bo = (size_t)(ct * 16 + cbase) * 512 + k0 + kofs;
      bf16x8 bh = *(const bf16x8*)(wt_hi + bo);
      bf16x8 bl = *(const bf16x8*)(wt_lo + bo);
      acc[ct] = __builtin_amdgcn_mfma_f32_16x16x32_bf16(ah, bh, acc[ct], 0, 0, 0);
      acc[ct] = __builtin_amdgcn_mfma_f32_16x16x32_bf16(al, bh, acc[ct], 0, 0, 0);
      acc[ct] = __builtin_amdgcn_mfma_f32_16x16x32_bf16(ah, bl, acc[ct], 0, 0, 0);
    }
  }
  // D: col = lane&15, row = (lane>>4)*4 + j
#pragma unroll
  for (int ct = 0; ct < 4; ++ct) {
#pragma unroll
    for (int j = 0; j < 4; ++j) {
      int r = r0 + (lane >> 4) * 4 + j;
      if (r < N) h1[(size_t)r * 64 + ct * 16 + cbase] = acc[ct][j];
    }
  }
}

// -------------------- per-node attention scalars, layer 1 --------------------
__global__ __launch_bounds__(256) void att1_kernel(const float* __restrict__ h1,
                                                   const float* __restrict__ atts,
                                                   const float* __restrict__ attd,
                                                   float* __restrict__ a1s, float* __restrict__ a1d, int N) {
  int gid = blockIdx.x * 256 + threadIdx.x;
  if (gid >= N * 8) return;
  int n = gid >> 3, h = gid & 7;
  const float* hp = h1 + (size_t)n * 64 + h * 8;
  float s = 0.f, d = 0.f;
#pragma unroll
  for (int c = 0; c < 8; ++c) {
    s = fmaf(hp[c], atts[h * 8 + c], s);
    d = fmaf(hp[c], attd[h * 8 + c], d);
  }
  a1s[gid] = s;
  a1d[gid] = d;
}

// -------------------- CSR build --------------------
__global__ __launch_bounds__(256) void init_deg_kernel(int* __restrict__ deg, int N) {
  int i = blockIdx.x * 256 + threadIdx.x;
  if (i < N) deg[i] = 1;  // self-loop
}

__global__ __launch_bounds__(256) void count_kernel(const int* __restrict__ ei, int E, int* __restrict__ deg) {
  int e = blockIdx.x * 256 + threadIdx.x;
  if (e < E) atomicAdd(&deg[ei[E + e]], 1);
}

__global__ __launch_bounds__(256) void scan1_kernel(int* __restrict__ data, int* __restrict__ blocksum, int N) {
  __shared__ int wave_tot[4];
  int t = threadIdx.x;
  int base = blockIdx.x * 1024;
  int v[4];
  int sum = 0;
#pragma unroll
  for (int i = 0; i < 4; ++i) {
    int idx = base + t * 4 + i;
    v[i] = sum;
    int d = (idx < N) ? data[idx] : 0;
    sum += d;
  }
  int lane = t & 63, wv = t >> 6;
  int x = sum;
#pragma unroll
  for (int ofs = 1; ofs < 64; ofs <<= 1) {
    int y = __shfl_up(x, ofs);
    if (lane >= ofs) x += y;
  }
  if (lane == 63) wave_tot[wv] = x;
  __syncthreads();
  int wofs = 0;
  for (int w = 0; w < wv; ++w) wofs += wave_tot[w];
  int excl_thread = wofs + x - sum;
#pragma unroll
  for (int i = 0; i < 4; ++i) {
    int idx = base + t * 4 + i;
    if (idx < N) data[idx] = excl_thread + v[i];
  }
  if (t == 255) blocksum[blockIdx.x] = wofs + x;
}

__global__ __launch_bounds__(256) void scan2_kernel(int* __restrict__ blocksum, int nb) {
  __shared__ int sm[256];
  int t = threadIdx.x;
  int x = (t < nb) ? blocksum[t] : 0;
  sm[t] = x;
  __syncthreads();
  for (int ofs = 1; ofs < 256; ofs <<= 1) {
    int y = (t >= ofs) ? sm[t - ofs] : 0;
    __syncthreads();
    sm[t] += y;
    __syncthreads();
  }
  if (t < nb) blocksum[t] = sm[t] - x;  // exclusive
}

__global__ __launch_bounds__(256) void scan3_kernel(const int* __restrict__ excl, const int* __restrict__ blocksum,
                                                    int* __restrict__ rowptr, int* __restrict__ cursor,
                                                    int N, int ET) {
  int idx = blockIdx.x * 256 + threadIdx.x;
  if (idx < N) {
    int r = excl[idx] + blocksum[idx >> 10];
    rowptr[idx] = r;
    cursor[idx] = r;
  }
  if (idx == N) rowptr[N] = ET;
}

// XCD-class-filtered scatter (keeps cursor/esrc writes XCD-local)
__global__ __launch_bounds__(256) void scatter_kernel(const int* __restrict__ ei, int E, int ET,
                                                      int* __restrict__ cursor, int* __restrict__ esrc, int N) {
  const int cls = blockIdx.x & 7;
  const int nlo = (int)(((long long)N * cls) >> 3);
  const int nhi = (int)(((long long)N * (cls + 1)) >> 3);
  const int chunk = blockIdx.x >> 3;
  const int nchunks = gridDim.x >> 3;
  const long long stride = (long long)nchunks * 256;
  for (long long e = (long long)chunk * 256 + threadIdx.x; e < ET; e += stride) {
    int s, d;
    if (e < E) { d = ei[E + e]; s = ei[e]; }
    else       { d = (int)(e - E); s = d; }
    if (d >= nlo && d < nhi) {
      int pos = atomicAdd(&cursor[d], 1);
      esrc[pos] = s;
    }
  }
}

// -------------------- layer-1 aggregation: wave per dst node, lane = channel --------------------
__global__ __launch_bounds__(256) void agg1_kernel(const int* __restrict__ rowptr, const int* __restrict__ esrc,
                                                   const float* __restrict__ a1s, const float* __restrict__ a1d,
                                                   const float* __restrict__ h1, const float* __restrict__ bias1,
                                                   float* __restrict__ h2, int N) {
  int wid = (blockIdx.x * 256 + threadIdx.x) >> 6;
  int lane = threadIdx.x & 63;
  if (wid >= N) return;
  int n = wid;
  int h = lane >> 3;
  float ad = a1d[n * 8 + h];
  int beg = rowptr[n], end = rowptr[n + 1];
  float acc = 0.f, wsum = 0.f;
  int k = beg;
  for (; k + 1 < end; k += 2) {
    int s0 = esrc[k], s1 = esrc[k + 1];
    float al0 = a1s[s0 * 8 + h] + ad;
    float al1 = a1s[s1 * 8 + h] + ad;
    float g0 = h1[(size_t)s0 * 64 + lane];
    float g1 = h1[(size_t)s1 * 64 + lane];
    al0 = (al0 > 0.f) ? al0 : NEG_SLOPE * al0;
    al1 = (al1 > 0.f) ? al1 : NEG_SLOPE * al1;
    float w0 = __expf(al0), w1 = __expf(al1);
    acc = fmaf(w0, g0, acc);
    acc = fmaf(w1, g1, acc);
    wsum += w0 + w1;
  }
  if (k < end) {
    int s0 = esrc[k];
    float al0 = a1s[s0 * 8 + h] + ad;
    float g0 = h1[(size_t)s0 * 64 + lane];
    al0 = (al0 > 0.f) ? al0 : NEG_SLOPE * al0;
    float w0 = __expf(al0);
    acc = fmaf(w0, g0, acc);
    wsum += w0;
  }
  float v = acc / (wsum + EPSF) + bias1[lane];
  h2[(size_t)n * 64 + lane] = (v > 0.f) ? v : expm1f(v);
}

// -------------------- layer2 projection g = h2 @ W2 + attention scalars --------------------
__global__ __launch_bounds__(256) void l2_proj_kernel(const float* __restrict__ h2, const float* __restrict__ W2,
                                                      const float* __restrict__ atts, const float* __restrict__ attd,
                                                      float* __restrict__ g, float* __restrict__ a2s,
                                                      float* __restrict__ a2d, int N) {
  __shared__ float w[1024];
  int tid = threadIdx.x;
  for (int i = tid; i < 1024; i += 256) w[i] = W2[i];
  __syncthreads();
  int gid = blockIdx.x * 256 + tid;
  int n = gid >> 4, c = gid & 15;
  if (n >= N) return;
  const float* hr = h2 + (size_t)n * 64;
  float acc = 0.f;
#pragma unroll
  for (int k = 0; k < 64; ++k) acc = fmaf(hr[k], w[k * 16 + c], acc);
  g[(size_t)n * 16 + c] = acc;
  float ps = acc * atts[c], pd = acc * attd[c];
#pragma unroll
  for (int m = 1; m < 16; m <<= 1) { ps += __shfl_xor(ps, m); pd += __shfl_xor(pd, m); }
  if (c == 0) { a2s[n] = ps; a2d[n] = pd; }
}

// -------------------- layer-2 aggregation + bias + softmax (fused final) --------------------
__global__ __launch_bounds__(256) void agg2_kernel(const int* __restrict__ rowptr, const int* __restrict__ esrc,
                                                   const float* __restrict__ a2s, const float* __restrict__ a2d,
                                                   const float* __restrict__ g, const float* __restrict__ bias2,
                                                   float* __restrict__ out_sm, float* __restrict__ emb, int N) {
  int wid = (blockIdx.x * 256 + threadIdx.x) >> 6;
  int lane = threadIdx.x & 63;
  if (wid >= N) return;
  int n = wid;
  int c = lane & 15, sub = lane >> 4;
  float ad = a2d[n];
  int beg = rowptr[n], end = rowptr[n + 1];
  float acc = 0.f, wsum = 0.f;
  for (int k = beg + sub; k < end; k += 4) {
    int s = esrc[k];
    float al = a2s[s] + ad;
    al = (al > 0.f) ? al : NEG_SLOPE * al;
    float w = __expf(al);
    acc = fmaf(w, g[(size_t)s * 16 + c], acc);
    wsum += w;
  }
  acc += __shfl_xor(acc, 16); acc += __shfl_xor(acc, 32);
  wsum += __shfl_xor(wsum, 16); wsum += __shfl_xor(wsum, 32);
  float v = acc / (wsum + EPSF) + bias2[c];
  float m = v;
#pragma unroll
  for (int k2 = 1; k2 < 16; k2 <<= 1) m = fmaxf(m, __shfl_xor(m, k2));
  float e = __expf(v - m);
  float ssum = e;
#pragma unroll
  for (int k2 = 1; k2 < 16; k2 <<= 1) ssum += __shfl_xor(ssum, k2);
  if (sub == 0) {
    emb[(size_t)n * 16 + c] = v;
    out_sm[(size_t)n * 16 + c] = e / ssum;
  }
}

extern "C" void kernel_launch(void* const* d_in, const int* in_sizes, int n_in,
                              void* d_out, int out_size, void* d_ws, size_t ws_size,
                              hipStream_t stream) {
  const float* x     = (const float*)d_in[0];
  const int*   ei    = (const int*)d_in[1];
  const float* W1    = (const float*)d_in[2];
  const float* atts1 = (const float*)d_in[3];
  const float* attd1 = (const float*)d_in[4];
  const float* bias1 = (const float*)d_in[5];
  const float* W2    = (const float*)d_in[6];
  const float* atts2 = (const float*)d_in[7];
  const float* attd2 = (const float*)d_in[8];
  const float* bias2 = (const float*)d_in[9];

  const int N = in_sizes[0] / 512;
  const int E = in_sizes[1] / 2;
  const int ET = E + N;

  // workspace layout (4-byte elems). g/a2s/a2d alias h1; wt_hi/lo alias h2 (dead until agg1).
  float* ws   = (float*)d_ws;
  float* h1   = ws;                       // N*64  (later reused: g N*16, a2s N, a2d N)
  float* a1s  = h1  + (size_t)N * 64;     // N*8
  float* a1d  = a1s + (size_t)N * 8;      // N*8
  float* h2   = a1d + (size_t)N * 8;      // N*64
  int*   deg  = (int*)(h2 + (size_t)N * 64); // N (in-place becomes excl-scan)
  int*   rowptr = deg + N;                // N+1
  int*   cursor = rowptr + N + 1;         // N
  int*   blocksum = cursor + N;           // 256
  int*   esrc = blocksum + 256;           // ET

  unsigned short* wt_hi = (unsigned short*)h2;  // 64*512 ushorts (aliases h2, dead by agg1)
  unsigned short* wt_lo = wt_hi + 64 * 512;

  float* g   = h1;                        // N*16 (aliases h1)
  float* a2s = h1 + (size_t)N * 16;       // N
  float* a2d = a2s + N;                   // N

  float* out_sm = (float*)d_out;            // softmax output [N,16]
  float* emb    = out_sm + (size_t)N * 16;  // node_embeddings [N,16]

  const int nb = (N + 1023) / 1024;

  // CSR build
  init_deg_kernel<<<(N + 255) / 256, 256, 0, stream>>>(deg, N);
  count_kernel<<<(E + 255) / 256, 256, 0, stream>>>(ei, E, deg);
  scan1_kernel<<<nb, 256, 0, stream>>>(deg, blocksum, N);
  scan2_kernel<<<1, 256, 0, stream>>>(blocksum, nb);
  scan3_kernel<<<(N + 256) / 256, 256, 0, stream>>>(deg, blocksum, rowptr, cursor, N, ET);
  scatter_kernel<<<8 * 1024, 256, 0, stream>>>(ei, E, ET, cursor, esrc, N);

  // layer 1: MFMA gemm (LDS-free) + attention scalars
  prep_w_kernel<<<128, 256, 0, stream>>>(W1, wt_hi, wt_lo);
  {
    int ntiles = (N + 15) / 16;
    gemm1_kernel<<<(ntiles + 3) / 4, 256, 0, stream>>>(x, wt_hi, wt_lo, h1, N);
  }
  att1_kernel<<<(N * 8 + 255) / 256, 256, 0, stream>>>(h1, atts1, attd1, a1s, a1d, N);
  agg1_kernel<<<(N + 3) / 4, 256, 0, stream>>>(rowptr, esrc, a1s, a1d, h1, bias1, h2, N);

  // layer 2
  l2_proj_kernel<<<(N * 16 + 255) / 256, 256, 0, stream>>>(h2, W2, atts2, attd2, g, a2s, a2d, N);
  agg2_kernel<<<(N + 3) / 4, 256, 0, stream>>>(rowptr, esrc, a2s, a2d, g, bias2, out_sm, emb, N);
}

// Round 6
// 476.529 us; speedup vs baseline: 1.0054x; 1.0054x over previous
//
#include <hip/hip_runtime.h>
#include <hip/hip_bf16.h>

#define NEG_SLOPE 0.2f
#define EPSF 1e-16f

typedef __attribute__((ext_vector_type(8))) short bf16x8;
typedef __attribute__((ext_vector_type(4))) float f32x4;

__device__ inline unsigned short f2bf(float x) {
  unsigned int u = __float_as_uint(x);
  return (unsigned short)((u + 0x7fffu + ((u >> 16) & 1u)) >> 16);
}
__device__ inline float bf2f(unsigned short h) {
  return __uint_as_float(((unsigned int)h) << 16);
}

// -------------------- W prep: Wt_{hi,lo}[c][k] bf16 (linear transpose) --------------------
__global__ __launch_bounds__(256) void prep_w_kernel(const float* __restrict__ W,
                                                     unsigned short* __restrict__ wt_hi,
                                                     unsigned short* __restrict__ wt_lo) {
  int idx = blockIdx.x * 256 + threadIdx.x;  // (k:512, c:64)
  if (idx >= 512 * 64) return;
  int k = idx >> 6, c = idx & 63;
  float w = W[idx];
  unsigned short h = f2bf(w);
  unsigned short l = f2bf(w - bf2f(h));
  wt_hi[c * 512 + k] = h;
  wt_lo[c * 512 + k] = l;
}

// -------------------- GEMM1 via bf16 MFMA, LDS-free, branchless software pipeline --------------------
// wave owns rows [wtile*16, +16) x all 64 cols. A straight from x (coalesced, read-once);
// B from L2-resident pre-transposed Wt hi/lo. Explicit 1-deep prefetch, fully unrolled,
// zero control flow in the loop -> compiler keeps >=10 loads in flight per wave.
__global__ __launch_bounds__(256, 4) void gemm1_kernel(const float* __restrict__ x,
                                                       const unsigned short* __restrict__ wt_hi,
                                                       const unsigned short* __restrict__ wt_lo,
                                                       float* __restrict__ h1, int N) {
  const int lane = threadIdx.x & 63;
  const int wtile = (blockIdx.x * 256 + threadIdx.x) >> 6;  // global wave id
  const int r0 = wtile * 16;
  if (r0 >= N) return;
  int rowA = r0 + (lane & 15);
  if (rowA >= N) rowA = N - 1;  // hoisted clamp; loop below is branchless
  const int kofs = (lane >> 4) * 8;
  const float* ap = x + (size_t)rowA * 512 + kofs;
  const int cbase = lane & 15;
  const unsigned short* bph = wt_hi + (size_t)cbase * 512 + kofs;
  const unsigned short* bpl = wt_lo + (size_t)cbase * 512 + kofs;

  f32x4 acc[4] = {};

  // prologue loads (k0 = 0)
  float4 a0 = *(const float4*)(ap);
  float4 a1 = *(const float4*)(ap + 4);
  bf16x8 bh[4], bl[4];
#pragma unroll
  for (int ct = 0; ct < 4; ++ct) {
    bh[ct] = *(const bf16x8*)(bph + ct * 16 * 512);
    bl[ct] = *(const bf16x8*)(bpl + ct * 16 * 512);
  }

#pragma unroll
  for (int k0 = 0; k0 < 512; k0 += 32) {
    const int kn = (k0 + 32 < 512) ? (k0 + 32) : 0;  // last iter: harmless dummy reload
    // ---- prefetch next iteration ----
    float4 na0 = *(const float4*)(ap + kn);
    float4 na1 = *(const float4*)(ap + kn + 4);
    bf16x8 nbh[4], nbl[4];
#pragma unroll
    for (int ct = 0; ct < 4; ++ct) {
      nbh[ct] = *(const bf16x8*)(bph + ct * 16 * 512 + kn);
      nbl[ct] = *(const bf16x8*)(bpl + ct * 16 * 512 + kn);
    }
    // ---- convert current A to bf16 hi/lo (truncation split) ----
    float av[8] = {a0.x, a0.y, a0.z, a0.w, a1.x, a1.y, a1.z, a1.w};
    bf16x8 ah, al;
#pragma unroll
    for (int j = 0; j < 8; ++j) {
      unsigned int u = __float_as_uint(av[j]);
      ah[j] = (short)(unsigned short)(u >> 16);
      float lo = av[j] - __uint_as_float(u & 0xffff0000u);
      al[j] = (short)(unsigned short)(__float_as_uint(lo) >> 16);
    }
    // ---- MFMA: hi*hi + lo*hi + hi*lo ----
#pragma unroll
    for (int ct = 0; ct < 4; ++ct) {
      acc[ct] = __builtin_amdgcn_mfma_f32_16x16x32_bf16(ah, bh[ct], acc[ct], 0, 0, 0);
      acc[ct] = __builtin_amdgcn_mfma_f32_16x16x32_bf16(al, bh[ct], acc[ct], 0, 0, 0);
      acc[ct] = __builtin_amdgcn_mfma_f32_16x16x32_bf16(ah, bl[ct], acc[ct], 0, 0, 0);
    }
    // ---- rotate (register renames under full unroll) ----
    a0 = na0; a1 = na1;
#pragma unroll
    for (int ct = 0; ct < 4; ++ct) { bh[ct] = nbh[ct]; bl[ct] = nbl[ct]; }
  }

  // D: col = lane&15, row = (lane>>4)*4 + j
#pragma unroll
  for (int ct = 0; ct < 4; ++ct) {
#pragma unroll
    for (int j = 0; j < 4; ++j) {
      int r = r0 + (lane >> 4) * 4 + j;
      if (r < N) h1[(size_t)r * 64 + ct * 16 + cbase] = acc[ct][j];
    }
  }
}

// -------------------- per-node attention scalars, layer 1 --------------------
__global__ __launch_bounds__(256) void att1_kernel(const float* __restrict__ h1,
                                                   const float* __restrict__ atts,
                                                   const float* __restrict__ attd,
                                                   float* __restrict__ a1s, float* __restrict__ a1d, int N) {
  int gid = blockIdx.x * 256 + threadIdx.x;
  if (gid >= N * 8) return;
  int n = gid >> 3, h = gid & 7;
  const float* hp = h1 + (size_t)n * 64 + h * 8;
  float s = 0.f, d = 0.f;
#pragma unroll
  for (int c = 0; c < 8; ++c) {
    s = fmaf(hp[c], atts[h * 8 + c], s);
    d = fmaf(hp[c], attd[h * 8 + c], d);
  }
  a1s[gid] = s;
  a1d[gid] = d;
}

// -------------------- CSR build --------------------
__global__ __launch_bounds__(256) void init_deg_kernel(int* __restrict__ deg, int N) {
  int i = blockIdx.x * 256 + threadIdx.x;
  if (i < N) deg[i] = 1;  // self-loop
}

__global__ __launch_bounds__(256) void count_kernel(const int* __restrict__ ei, int E, int* __restrict__ deg) {
  int e = blockIdx.x * 256 + threadIdx.x;
  if (e < E) atomicAdd(&deg[ei[E + e]], 1);
}

__global__ __launch_bounds__(256) void scan1_kernel(int* __restrict__ data, int* __restrict__ blocksum, int N) {
  __shared__ int wave_tot[4];
  int t = threadIdx.x;
  int base = blockIdx.x * 1024;
  int v[4];
  int sum = 0;
#pragma unroll
  for (int i = 0; i < 4; ++i) {
    int idx = base + t * 4 + i;
    v[i] = sum;
    int d = (idx < N) ? data[idx] : 0;
    sum += d;
  }
  int lane = t & 63, wv = t >> 6;
  int x = sum;
#pragma unroll
  for (int ofs = 1; ofs < 64; ofs <<= 1) {
    int y = __shfl_up(x, ofs);
    if (lane >= ofs) x += y;
  }
  if (lane == 63) wave_tot[wv] = x;
  __syncthreads();
  int wofs = 0;
  for (int w = 0; w < wv; ++w) wofs += wave_tot[w];
  int excl_thread = wofs + x - sum;
#pragma unroll
  for (int i = 0; i < 4; ++i) {
    int idx = base + t * 4 + i;
    if (idx < N) data[idx] = excl_thread + v[i];
  }
  if (t == 255) blocksum[blockIdx.x] = wofs + x;
}

__global__ __launch_bounds__(256) void scan2_kernel(int* __restrict__ blocksum, int nb) {
  __shared__ int sm[256];
  int t = threadIdx.x;
  int x = (t < nb) ? blocksum[t] : 0;
  sm[t] = x;
  __syncthreads();
  for (int ofs = 1; ofs < 256; ofs <<= 1) {
    int y = (t >= ofs) ? sm[t - ofs] : 0;
    __syncthreads();
    sm[t] += y;
    __syncthreads();
  }
  if (t < nb) blocksum[t] = sm[t] - x;  // exclusive
}

__global__ __launch_bounds__(256) void scan3_kernel(const int* __restrict__ excl, const int* __restrict__ blocksum,
                                                    int* __restrict__ rowptr, int* __restrict__ cursor,
                                                    int N, int ET) {
  int idx = blockIdx.x * 256 + threadIdx.x;
  if (idx < N) {
    int r = excl[idx] + blocksum[idx >> 10];
    rowptr[idx] = r;
    cursor[idx] = r;
  }
  if (idx == N) rowptr[N] = ET;
}

// XCD-class-filtered scatter (keeps cursor/esrc writes XCD-local)
__global__ __launch_bounds__(256) void scatter_kernel(const int* __restrict__ ei, int E, int ET,
                                                      int* __restrict__ cursor, int* __restrict__ esrc, int N) {
  const int cls = blockIdx.x & 7;
  const int nlo = (int)(((long long)N * cls) >> 3);
  const int nhi = (int)(((long long)N * (cls + 1)) >> 3);
  const int chunk = blockIdx.x >> 3;
  const int nchunks = gridDim.x >> 3;
  const long long stride = (long long)nchunks * 256;
  for (long long e = (long long)chunk * 256 + threadIdx.x; e < ET; e += stride) {
    int s, d;
    if (e < E) { d = ei[E + e]; s = ei[e]; }
    else       { d = (int)(e - E); s = d; }
    if (d >= nlo && d < nhi) {
      int pos = atomicAdd(&cursor[d], 1);
      esrc[pos] = s;
    }
  }
}

// -------------------- layer-1 aggregation: wave per dst node, lane = channel --------------------
__global__ __launch_bounds__(256) void agg1_kernel(const int* __restrict__ rowptr, const int* __restrict__ esrc,
                                                   const float* __restrict__ a1s, const float* __restrict__ a1d,
                                                   const float* __restrict__ h1, const float* __restrict__ bias1,
                                                   float* __restrict__ h2, int N) {
  int wid = (blockIdx.x * 256 + threadIdx.x) >> 6;
  int lane = threadIdx.x & 63;
  if (wid >= N) return;
  int n = wid;
  int h = lane >> 3;
  float ad = a1d[n * 8 + h];
  int beg = rowptr[n], end = rowptr[n + 1];
  float acc = 0.f, wsum = 0.f;
  int k = beg;
  for (; k + 1 < end; k += 2) {
    int s0 = esrc[k], s1 = esrc[k + 1];
    float al0 = a1s[s0 * 8 + h] + ad;
    float al1 = a1s[s1 * 8 + h] + ad;
    float g0 = h1[(size_t)s0 * 64 + lane];
    float g1 = h1[(size_t)s1 * 64 + lane];
    al0 = (al0 > 0.f) ? al0 : NEG_SLOPE * al0;
    al1 = (al1 > 0.f) ? al1 : NEG_SLOPE * al1;
    float w0 = __expf(al0), w1 = __expf(al1);
    acc = fmaf(w0, g0, acc);
    acc = fmaf(w1, g1, acc);
    wsum += w0 + w1;
  }
  if (k < end) {
    int s0 = esrc[k];
    float al0 = a1s[s0 * 8 + h] + ad;
    float g0 = h1[(size_t)s0 * 64 + lane];
    al0 = (al0 > 0.f) ? al0 : NEG_SLOPE * al0;
    float w0 = __expf(al0);
    acc = fmaf(w0, g0, acc);
    wsum += w0;
  }
  float v = acc / (wsum + EPSF) + bias1[lane];
  h2[(size_t)n * 64 + lane] = (v > 0.f) ? v : expm1f(v);
}

// -------------------- layer2 projection g = h2 @ W2 + attention scalars --------------------
__global__ __launch_bounds__(256) void l2_proj_kernel(const float* __restrict__ h2, const float* __restrict__ W2,
                                                      const float* __restrict__ atts, const float* __restrict__ attd,
                                                      float* __restrict__ g, float* __restrict__ a2s,
                                                      float* __restrict__ a2d, int N) {
  __shared__ float w[1024];
  int tid = threadIdx.x;
  for (int i = tid; i < 1024; i += 256) w[i] = W2[i];
  __syncthreads();
  int gid = blockIdx.x * 256 + tid;
  int n = gid >> 4, c = gid & 15;
  if (n >= N) return;
  const float* hr = h2 + (size_t)n * 64;
  float acc = 0.f;
#pragma unroll
  for (int k = 0; k < 64; ++k) acc = fmaf(hr[k], w[k * 16 + c], acc);
  g[(size_t)n * 16 + c] = acc;
  float ps = acc * atts[c], pd = acc * attd[c];
#pragma unroll
  for (int m = 1; m < 16; m <<= 1) { ps += __shfl_xor(ps, m); pd += __shfl_xor(pd, m); }
  if (c == 0) { a2s[n] = ps; a2d[n] = pd; }
}

// -------------------- layer-2 aggregation + bias + softmax (fused final) --------------------
__global__ __launch_bounds__(256) void agg2_kernel(const int* __restrict__ rowptr, const int* __restrict__ esrc,
                                                   const float* __restrict__ a2s, const float* __restrict__ a2d,
                                                   const float* __restrict__ g, const float* __restrict__ bias2,
                                                   float* __restrict__ out_sm, float* __restrict__ emb, int N) {
  int wid = (blockIdx.x * 256 + threadIdx.x) >> 6;
  int lane = threadIdx.x & 63;
  if (wid >= N) return;
  int n = wid;
  int c = lane & 15, sub = lane >> 4;
  float ad = a2d[n];
  int beg = rowptr[n], end = rowptr[n + 1];
  float acc = 0.f, wsum = 0.f;
  for (int k = beg + sub; k < end; k += 4) {
    int s = esrc[k];
    float al = a2s[s] + ad;
    al = (al > 0.f) ? al : NEG_SLOPE * al;
    float w = __expf(al);
    acc = fmaf(w, g[(size_t)s * 16 + c], acc);
    wsum += w;
  }
  acc += __shfl_xor(acc, 16); acc += __shfl_xor(acc, 32);
  wsum += __shfl_xor(wsum, 16); wsum += __shfl_xor(wsum, 32);
  float v = acc / (wsum + EPSF) + bias2[c];
  float m = v;
#pragma unroll
  for (int k2 = 1; k2 < 16; k2 <<= 1) m = fmaxf(m, __shfl_xor(m, k2));
  float e = __expf(v - m);
  float ssum = e;
#pragma unroll
  for (int k2 = 1; k2 < 16; k2 <<= 1) ssum += __shfl_xor(ssum, k2);
  if (sub == 0) {
    emb[(size_t)n * 16 + c] = v;
    out_sm[(size_t)n * 16 + c] = e / ssum;
  }
}

extern "C" void kernel_launch(void* const* d_in, const int* in_sizes, int n_in,
                              void* d_out, int out_size, void* d_ws, size_t ws_size,
                              hipStream_t stream) {
  const float* x     = (const float*)d_in[0];
  const int*   ei    = (const int*)d_in[1];
  const float* W1    = (const float*)d_in[2];
  const float* atts1 = (const float*)d_in[3];
  const float* attd1 = (const float*)d_in[4];
  const float* bias1 = (const float*)d_in[5];
  const float* W2    = (const float*)d_in[6];
  const float* atts2 = (const float*)d_in[7];
  const float* attd2 = (const float*)d_in[8];
  const float* bias2 = (const float*)d_in[9];

  const int N = in_sizes[0] / 512;
  const int E = in_sizes[1] / 2;
  const int ET = E + N;

  // workspace layout (4-byte elems). g/a2s/a2d alias h1; wt_hi/lo alias h2 (dead until agg1).
  float* ws   = (float*)d_ws;
  float* h1   = ws;                       // N*64  (later reused: g N*16, a2s N, a2d N)
  float* a1s  = h1  + (size_t)N * 64;     // N*8
  float* a1d  = a1s + (size_t)N * 8;      // N*8
  float* h2   = a1d + (size_t)N * 8;      // N*64
  int*   deg  = (int*)(h2 + (size_t)N * 64); // N (in-place becomes excl-scan)
  int*   rowptr = deg + N;                // N+1
  int*   cursor = rowptr + N + 1;         // N
  int*   blocksum = cursor + N;           // 256
  int*   esrc = blocksum + 256;           // ET

  unsigned short* wt_hi = (unsigned short*)h2;  // 64*512 ushorts (aliases h2, dead by agg1)
  unsigned short* wt_lo = wt_hi + 64 * 512;

  float* g   = h1;                        // N*16 (aliases h1)
  float* a2s = h1 + (size_t)N * 16;       // N
  float* a2d = a2s + N;                   // N

  float* out_sm = (float*)d_out;            // softmax output [N,16]
  float* emb    = out_sm + (size_t)N * 16;  // node_embeddings [N,16]

  const int nb = (N + 1023) / 1024;

  // CSR build
  init_deg_kernel<<<(N + 255) / 256, 256, 0, stream>>>(deg, N);
  count_kernel<<<(E + 255) / 256, 256, 0, stream>>>(ei, E, deg);
  scan1_kernel<<<nb, 256, 0, stream>>>(deg, blocksum, N);
  scan2_kernel<<<1, 256, 0, stream>>>(blocksum, nb);
  scan3_kernel<<<(N + 256) / 256, 256, 0, stream>>>(deg, blocksum, rowptr, cursor, N, ET);
  scatter_kernel<<<8 * 1024, 256, 0, stream>>>(ei, E, ET, cursor, esrc, N);

  // layer 1: MFMA gemm (LDS-free, pipelined) + attention scalars
  prep_w_kernel<<<128, 256, 0, stream>>>(W1, wt_hi, wt_lo);
  {
    int ntiles = (N + 15) / 16;
    gemm1_kernel<<<(ntiles + 3) / 4, 256, 0, stream>>>(x, wt_hi, wt_lo, h1, N);
  }
  att1_kernel<<<(N * 8 + 255) / 256, 256, 0, stream>>>(h1, atts1, attd1, a1s, a1d, N);
  agg1_kernel<<<(N + 3) / 4, 256, 0, stream>>>(rowptr, esrc, a1s, a1d, h1, bias1, h2, N);

  // layer 2
  l2_proj_kernel<<<(N * 16 + 255) / 256, 256, 0, stream>>>(h2, W2, atts2, attd2, g, a2s, a2d, N);
  agg2_kernel<<<(N + 3) / 4, 256, 0, stream>>>(rowptr, esrc, a2s, a2d, g, bias2, out_sm, emb, N);
}

// Round 7
// 397.649 us; speedup vs baseline: 1.2048x; 1.1984x over previous
//
#include <hip/hip_runtime.h>
#include <hip/hip_bf16.h>

#define NEG_SLOPE 0.2f
#define EPSF 1e-16f

typedef __attribute__((ext_vector_type(8))) short bf16x8;
typedef __attribute__((ext_vector_type(4))) float f32x4;

__device__ inline unsigned short f2bf(float x) {
  unsigned int u = __float_as_uint(x);
  return (unsigned short)((u + 0x7fffu + ((u >> 16) & 1u)) >> 16);
}
__device__ inline float bf2f(unsigned short h) {
  return __uint_as_float(((unsigned int)h) << 16);
}

__device__ __forceinline__ void gload16(const void* src, void* dst) {
  __builtin_amdgcn_global_load_lds(
      (const __attribute__((address_space(1))) unsigned int*)src,
      (__attribute__((address_space(3))) unsigned int*)dst, 16, 0, 0);
}

// -------------------- W prep: chunked pre-swizzled B slabs --------------------
// wb[ch] = 8KB: hi slab 4KB then lo slab 4KB. Element (c,kin) of chunk ch stored at
// byte A' = ((c*64 + kin*2) ^ ((c&7)<<4)) within slab (XOR-swizzle for conflict-free
// ds_read_b128; staging copies linearly so prep pre-applies the swizzle).
__global__ __launch_bounds__(256) void prep_w_kernel(const float* __restrict__ W,
                                                     unsigned short* __restrict__ wb) {
  int idx = blockIdx.x * 256 + threadIdx.x;  // (k:512, c:64)
  if (idx >= 512 * 64) return;
  int k = idx >> 6, c = idx & 63;
  float w = W[idx];
  unsigned short h = f2bf(w);
  unsigned short l = f2bf(w - bf2f(h));
  int ch = k >> 5, kin = k & 31;
  int Ap = ((c << 6) + (kin << 1)) ^ ((c & 7) << 4);  // byte in 4KB slab
  wb[ch * 4096 + (Ap >> 1)] = h;
  wb[ch * 4096 + 2048 + (Ap >> 1)] = l;
}

// -------------------- GEMM1: h1[N,64] = x[N,512] @ W1, bf16-MFMA split precision ----------
// 2-phase async pipeline: global_load_lds staging (A f32 swizzled-source, B pre-swizzled
// slabs), counted vmcnt(6), raw barriers. Tile 128x64, BK=32, 4 waves.
__global__ __launch_bounds__(256) void gemm1_kernel(const float* __restrict__ x,
                                                    const unsigned short* __restrict__ wb,
                                                    float* __restrict__ h1, int N) {
  __shared__ __align__(16) float As[2][4096];          // 2 x 128r x 32k f32 = 32 KB
  __shared__ __align__(16) unsigned short Bs[2][4096]; // 2 x (hi 2048 + lo 2048) = 16 KB
  const int tid = threadIdx.x, wv = tid >> 6, lane = tid & 63;
  const int row0 = blockIdx.x * 128;

  // ---- staging source/dest precompute ----
  // A: 1024 units of 16B; unit u -> row=u>>3, w=u&7; LDS linear; source pre-permuted:
  // LDS[row][w] = x[row][w ^ (row&7)] (16B units) so reads use the same XOR.
  const float* asrc[4];
  int aldo[4];
#pragma unroll
  for (int i = 0; i < 4; ++i) {
    int u = i * 256 + wv * 64 + lane;
    int row = u >> 3, w = u & 7;
    int rg = row0 + row;
    if (rg >= N) rg = N - 1;
    asrc[i] = x + (size_t)rg * 512 + ((w ^ (row & 7)) << 2);
    aldo[i] = (i * 256 + wv * 64) * 4;  // float offset (wave-uniform)
  }
  const unsigned short* bsrc[2];
  int bldo[2];
#pragma unroll
  for (int i = 0; i < 2; ++i) {
    int u = i * 256 + wv * 64 + lane;
    bsrc[i] = wb + (size_t)u * 8;
    bldo[i] = (i * 256 + wv * 64) * 8;  // ushort offset (wave-uniform)
  }

  // ---- read-address precompute (chunk-independent) ----
  const int kofs = (lane >> 4) * 8;  // k-float offset within 32
  const int cbase = lane & 15;
  int ardo[2][2];  // [row-frag][half] float index
#pragma unroll
  for (int rt = 0; rt < 2; ++rt) {
    int r = wv * 32 + rt * 16 + cbase;
#pragma unroll
    for (int h = 0; h < 2; ++h)
      ardo[rt][h] = r * 32 + ((((kofs >> 2) + h) ^ (r & 7)) << 2);
  }
  int brdo[4];  // ushort index in hi slab; lo = +2048
#pragma unroll
  for (int ct = 0; ct < 4; ++ct) {
    int c = ct * 16 + cbase;
    brdo[ct] = (((c << 6) + (kofs << 1)) ^ ((c & 7) << 4)) >> 1;
  }

  f32x4 acc[2][4] = {};

  auto stage = [&](int b, int ch) {
#pragma unroll
    for (int i = 0; i < 4; ++i) gload16(asrc[i] + ch * 32, &As[b][aldo[i]]);
#pragma unroll
    for (int i = 0; i < 2; ++i) gload16(bsrc[i] + ch * 4096, &Bs[b][bldo[i]]);
  };

  stage(0, 0);
  for (int ch = 0; ch < 16; ++ch) {
    const int b = ch & 1;
    if (ch < 15) {
      stage(b ^ 1, ch + 1);  // 6 more in flight (<=12 outstanding)
      asm volatile("s_waitcnt vmcnt(6)" ::: "memory");  // current chunk landed
    } else {
      asm volatile("s_waitcnt vmcnt(0)" ::: "memory");
    }
    __builtin_amdgcn_s_barrier();
    __builtin_amdgcn_sched_barrier(0);  // no ds_read hoists above the barrier

#pragma unroll
    for (int rt = 0; rt < 2; ++rt) {
      float4 a0 = *(const float4*)(&As[b][ardo[rt][0]]);
      float4 a1 = *(const float4*)(&As[b][ardo[rt][1]]);
      float av[8] = {a0.x, a0.y, a0.z, a0.w, a1.x, a1.y, a1.z, a1.w};
      bf16x8 ah, al;
#pragma unroll
      for (int j = 0; j < 8; ++j) {
        unsigned int u = __float_as_uint(av[j]);
        ah[j] = (short)(unsigned short)(u >> 16);
        float lo = av[j] - __uint_as_float(u & 0xffff0000u);
        al[j] = (short)(unsigned short)(__float_as_uint(lo) >> 16);
      }
#pragma unroll
      for (int ct = 0; ct < 4; ++ct) {
        bf16x8 bh = *(const bf16x8*)(&Bs[b][brdo[ct]]);
        bf16x8 bl = *(const bf16x8*)(&Bs[b][brdo[ct] + 2048]);
        acc[rt][ct] = __builtin_amdgcn_mfma_f32_16x16x32_bf16(ah, bh, acc[rt][ct], 0, 0, 0);
        acc[rt][ct] = __builtin_amdgcn_mfma_f32_16x16x32_bf16(al, bh, acc[rt][ct], 0, 0, 0);
        acc[rt][ct] = __builtin_amdgcn_mfma_f32_16x16x32_bf16(ah, bl, acc[rt][ct], 0, 0, 0);
      }
    }
    // all this wave's ds_reads serviced before anyone re-stages this buffer
    asm volatile("s_waitcnt lgkmcnt(0)" ::: "memory");
    __builtin_amdgcn_s_barrier();
  }

  // D: col = lane&15, row = (lane>>4)*4 + j
#pragma unroll
  for (int rt = 0; rt < 2; ++rt) {
#pragma unroll
    for (int ct = 0; ct < 4; ++ct) {
#pragma unroll
      for (int j = 0; j < 4; ++j) {
        int r = row0 + wv * 32 + rt * 16 + (lane >> 4) * 4 + j;
        if (r < N) h1[(size_t)r * 64 + ct * 16 + cbase] = acc[rt][ct][j];
      }
    }
  }
}

// -------------------- per-node attention scalars, layer 1 --------------------
__global__ __launch_bounds__(256) void att1_kernel(const float* __restrict__ h1,
                                                   const float* __restrict__ atts,
                                                   const float* __restrict__ attd,
                                                   float* __restrict__ a1s, float* __restrict__ a1d, int N) {
  int gid = blockIdx.x * 256 + threadIdx.x;
  if (gid >= N * 8) return;
  int n = gid >> 3, h = gid & 7;
  const float* hp = h1 + (size_t)n * 64 + h * 8;
  float s = 0.f, d = 0.f;
#pragma unroll
  for (int c = 0; c < 8; ++c) {
    s = fmaf(hp[c], atts[h * 8 + c], s);
    d = fmaf(hp[c], attd[h * 8 + c], d);
  }
  a1s[gid] = s;
  a1d[gid] = d;
}

// -------------------- CSR build --------------------
__global__ __launch_bounds__(256) void init_deg_kernel(int* __restrict__ deg, int N) {
  int i = blockIdx.x * 256 + threadIdx.x;
  if (i < N) deg[i] = 1;  // self-loop
}

__global__ __launch_bounds__(256) void count_kernel(const int* __restrict__ ei, int E, int* __restrict__ deg) {
  int e = blockIdx.x * 256 + threadIdx.x;
  if (e < E) atomicAdd(&deg[ei[E + e]], 1);
}

__global__ __launch_bounds__(256) void scan1_kernel(int* __restrict__ data, int* __restrict__ blocksum, int N) {
  __shared__ int wave_tot[4];
  int t = threadIdx.x;
  int base = blockIdx.x * 1024;
  int v[4];
  int sum = 0;
#pragma unroll
  for (int i = 0; i < 4; ++i) {
    int idx = base + t * 4 + i;
    v[i] = sum;
    int d = (idx < N) ? data[idx] : 0;
    sum += d;
  }
  int lane = t & 63, wv = t >> 6;
  int x = sum;
#pragma unroll
  for (int ofs = 1; ofs < 64; ofs <<= 1) {
    int y = __shfl_up(x, ofs);
    if (lane >= ofs) x += y;
  }
  if (lane == 63) wave_tot[wv] = x;
  __syncthreads();
  int wofs = 0;
  for (int w = 0; w < wv; ++w) wofs += wave_tot[w];
  int excl_thread = wofs + x - sum;
#pragma unroll
  for (int i = 0; i < 4; ++i) {
    int idx = base + t * 4 + i;
    if (idx < N) data[idx] = excl_thread + v[i];
  }
  if (t == 255) blocksum[blockIdx.x] = wofs + x;
}

__global__ __launch_bounds__(256) void scan2_kernel(int* __restrict__ blocksum, int nb) {
  __shared__ int sm[256];
  int t = threadIdx.x;
  int x = (t < nb) ? blocksum[t] : 0;
  sm[t] = x;
  __syncthreads();
  for (int ofs = 1; ofs < 256; ofs <<= 1) {
    int y = (t >= ofs) ? sm[t - ofs] : 0;
    __syncthreads();
    sm[t] += y;
    __syncthreads();
  }
  if (t < nb) blocksum[t] = sm[t] - x;  // exclusive
}

__global__ __launch_bounds__(256) void scan3_kernel(const int* __restrict__ excl, const int* __restrict__ blocksum,
                                                    int* __restrict__ rowptr, int* __restrict__ cursor,
                                                    int N, int ET) {
  int idx = blockIdx.x * 256 + threadIdx.x;
  if (idx < N) {
    int r = excl[idx] + blocksum[idx >> 10];
    rowptr[idx] = r;
    cursor[idx] = r;
  }
  if (idx == N) rowptr[N] = ET;
}

// XCD-class-filtered scatter (keeps cursor/esrc writes XCD-local)
__global__ __launch_bounds__(256) void scatter_kernel(const int* __restrict__ ei, int E, int ET,
                                                      int* __restrict__ cursor, int* __restrict__ esrc, int N) {
  const int cls = blockIdx.x & 7;
  const int nlo = (int)(((long long)N * cls) >> 3);
  const int nhi = (int)(((long long)N * (cls + 1)) >> 3);
  const int chunk = blockIdx.x >> 3;
  const int nchunks = gridDim.x >> 3;
  const long long stride = (long long)nchunks * 256;
  for (long long e = (long long)chunk * 256 + threadIdx.x; e < ET; e += stride) {
    int s, d;
    if (e < E) { d = ei[E + e]; s = ei[e]; }
    else       { d = (int)(e - E); s = d; }
    if (d >= nlo && d < nhi) {
      int pos = atomicAdd(&cursor[d], 1);
      esrc[pos] = s;
    }
  }
}

// -------------------- layer-1 aggregation: wave per dst node, lane = channel --------------------
__global__ __launch_bounds__(256) void agg1_kernel(const int* __restrict__ rowptr, const int* __restrict__ esrc,
                                                   const float* __restrict__ a1s, const float* __restrict__ a1d,
                                                   const float* __restrict__ h1, const float* __restrict__ bias1,
                                                   float* __restrict__ h2, int N) {
  int wid = (blockIdx.x * 256 + threadIdx.x) >> 6;
  int lane = threadIdx.x & 63;
  if (wid >= N) return;
  int n = wid;
  int h = lane >> 3;
  float ad = a1d[n * 8 + h];
  int beg = rowptr[n], end = rowptr[n + 1];
  float acc = 0.f, wsum = 0.f;
  int k = beg;
  for (; k + 1 < end; k += 2) {
    int s0 = esrc[k], s1 = esrc[k + 1];
    float al0 = a1s[s0 * 8 + h] + ad;
    float al1 = a1s[s1 * 8 + h] + ad;
    float g0 = h1[(size_t)s0 * 64 + lane];
    float g1 = h1[(size_t)s1 * 64 + lane];
    al0 = (al0 > 0.f) ? al0 : NEG_SLOPE * al0;
    al1 = (al1 > 0.f) ? al1 : NEG_SLOPE * al1;
    float w0 = __expf(al0), w1 = __expf(al1);
    acc = fmaf(w0, g0, acc);
    acc = fmaf(w1, g1, acc);
    wsum += w0 + w1;
  }
  if (k < end) {
    int s0 = esrc[k];
    float al0 = a1s[s0 * 8 + h] + ad;
    float g0 = h1[(size_t)s0 * 64 + lane];
    al0 = (al0 > 0.f) ? al0 : NEG_SLOPE * al0;
    float w0 = __expf(al0);
    acc = fmaf(w0, g0, acc);
    wsum += w0;
  }
  float v = acc / (wsum + EPSF) + bias1[lane];
  h2[(size_t)n * 64 + lane] = (v > 0.f) ? v : expm1f(v);
}

// -------------------- layer2 projection g = h2 @ W2 + attention scalars --------------------
__global__ __launch_bounds__(256) void l2_proj_kernel(const float* __restrict__ h2, const float* __restrict__ W2,
                                                      const float* __restrict__ atts, const float* __restrict__ attd,
                                                      float* __restrict__ g, float* __restrict__ a2s,
                                                      float* __restrict__ a2d, int N) {
  __shared__ float w[1024];
  int tid = threadIdx.x;
  for (int i = tid; i < 1024; i += 256) w[i] = W2[i];
  __syncthreads();
  int gid = blockIdx.x * 256 + tid;
  int n = gid >> 4, c = gid & 15;
  if (n >= N) return;
  const float* hr = h2 + (size_t)n * 64;
  float acc = 0.f;
#pragma unroll
  for (int k = 0; k < 64; ++k) acc = fmaf(hr[k], w[k * 16 + c], acc);
  g[(size_t)n * 16 + c] = acc;
  float ps = acc * atts[c], pd = acc * attd[c];
#pragma unroll
  for (int m = 1; m < 16; m <<= 1) { ps += __shfl_xor(ps, m); pd += __shfl_xor(pd, m); }
  if (c == 0) { a2s[n] = ps; a2d[n] = pd; }
}

// -------------------- layer-2 aggregation + bias + softmax (fused final) --------------------
__global__ __launch_bounds__(256) void agg2_kernel(const int* __restrict__ rowptr, const int* __restrict__ esrc,
                                                   const float* __restrict__ a2s, const float* __restrict__ a2d,
                                                   const float* __restrict__ g, const float* __restrict__ bias2,
                                                   float* __restrict__ out_sm, float* __restrict__ emb, int N) {
  int wid = (blockIdx.x * 256 + threadIdx.x) >> 6;
  int lane = threadIdx.x & 63;
  if (wid >= N) return;
  int n = wid;
  int c = lane & 15, sub = lane >> 4;
  float ad = a2d[n];
  int beg = rowptr[n], end = rowptr[n + 1];
  float acc = 0.f, wsum = 0.f;
  for (int k = beg + sub; k < end; k += 4) {
    int s = esrc[k];
    float al = a2s[s] + ad;
    al = (al > 0.f) ? al : NEG_SLOPE * al;
    float w = __expf(al);
    acc = fmaf(w, g[(size_t)s * 16 + c], acc);
    wsum += w;
  }
  acc += __shfl_xor(acc, 16); acc += __shfl_xor(acc, 32);
  wsum += __shfl_xor(wsum, 16); wsum += __shfl_xor(wsum, 32);
  float v = acc / (wsum + EPSF) + bias2[c];
  float m = v;
#pragma unroll
  for (int k2 = 1; k2 < 16; k2 <<= 1) m = fmaxf(m, __shfl_xor(m, k2));
  float e = __expf(v - m);
  float ssum = e;
#pragma unroll
  for (int k2 = 1; k2 < 16; k2 <<= 1) ssum += __shfl_xor(ssum, k2);
  if (sub == 0) {
    emb[(size_t)n * 16 + c] = v;
    out_sm[(size_t)n * 16 + c] = e / ssum;
  }
}

extern "C" void kernel_launch(void* const* d_in, const int* in_sizes, int n_in,
                              void* d_out, int out_size, void* d_ws, size_t ws_size,
                              hipStream_t stream) {
  const float* x     = (const float*)d_in[0];
  const int*   ei    = (const int*)d_in[1];
  const float* W1    = (const float*)d_in[2];
  const float* atts1 = (const float*)d_in[3];
  const float* attd1 = (const float*)d_in[4];
  const float* bias1 = (const float*)d_in[5];
  const float* W2    = (const float*)d_in[6];
  const float* atts2 = (const float*)d_in[7];
  const float* attd2 = (const float*)d_in[8];
  const float* bias2 = (const float*)d_in[9];

  const int N = in_sizes[0] / 512;
  const int E = in_sizes[1] / 2;
  const int ET = E + N;

  // workspace layout (4-byte elems). g/a2s/a2d alias h1; wb aliases h2 (dead until agg1).
  float* ws   = (float*)d_ws;
  float* h1   = ws;                       // N*64  (later reused: g N*16, a2s N, a2d N)
  float* a1s  = h1  + (size_t)N * 64;     // N*8
  float* a1d  = a1s + (size_t)N * 8;      // N*8
  float* h2   = a1d + (size_t)N * 8;      // N*64
  int*   deg  = (int*)(h2 + (size_t)N * 64); // N (in-place becomes excl-scan)
  int*   rowptr = deg + N;                // N+1
  int*   cursor = rowptr + N + 1;         // N
  int*   blocksum = cursor + N;           // 256
  int*   esrc = blocksum + 256;           // ET

  unsigned short* wb = (unsigned short*)h2;  // 16 chunks * 4096 ushorts = 128 KB (aliases h2)

  float* g   = h1;                        // N*16 (aliases h1)
  float* a2s = h1 + (size_t)N * 16;       // N
  float* a2d = a2s + N;                   // N

  float* out_sm = (float*)d_out;            // softmax output [N,16]
  float* emb    = out_sm + (size_t)N * 16;  // node_embeddings [N,16]

  const int nb = (N + 1023) / 1024;

  // CSR build
  init_deg_kernel<<<(N + 255) / 256, 256, 0, stream>>>(deg, N);
  count_kernel<<<(E + 255) / 256, 256, 0, stream>>>(ei, E, deg);
  scan1_kernel<<<nb, 256, 0, stream>>>(deg, blocksum, N);
  scan2_kernel<<<1, 256, 0, stream>>>(blocksum, nb);
  scan3_kernel<<<(N + 256) / 256, 256, 0, stream>>>(deg, blocksum, rowptr, cursor, N, ET);
  scatter_kernel<<<8 * 1024, 256, 0, stream>>>(ei, E, ET, cursor, esrc, N);

  // layer 1: MFMA gemm (async 2-phase pipeline) + attention scalars
  prep_w_kernel<<<128, 256, 0, stream>>>(W1, wb);
  gemm1_kernel<<<(N + 127) / 128, 256, 0, stream>>>(x, wb, h1, N);
  att1_kernel<<<(N * 8 + 255) / 256, 256, 0, stream>>>(h1, atts1, attd1, a1s, a1d, N);
  agg1_kernel<<<(N + 3) / 4, 256, 0, stream>>>(rowptr, esrc, a1s, a1d, h1, bias1, h2, N);

  // layer 2
  l2_proj_kernel<<<(N * 16 + 255) / 256, 256, 0, stream>>>(h2, W2, atts2, attd2, g, a2s, a2d, N);
  agg2_kernel<<<(N + 3) / 4, 256, 0, stream>>>(rowptr, esrc, a2s, a2d, g, bias2, out_sm, emb, N);
}